// Round 2
// baseline (651.865 us; speedup 1.0000x reference)
//
#include <hip/hip_runtime.h>

// Problem constants (from reference setup_inputs)
constexpr int Bb = 32;      // batch
constexpr int Mm = 65536;   // memory slots
constexpr int Ww = 32;      // word width
constexpr int Rr = 4;       // read heads
constexpr int Dd = 256;     // d_in
constexpr int Kk = 8;       // K_NEIGHBORS

constexpr int NB_A = 64;            // blocks per batch, phase A
constexpr int TPB_A = 256;          // threads per block, phase A
constexpr int ROWS_PER_BLOCK = Mm / NB_A;          // 1024
constexpr int QQ = ROWS_PER_BLOCK / TPB_A;         // 4 rows per thread

// ---------------------------------------------------------------------------
// Kernel 1: read_keys = xi @ W_rk^T + b_rk  (32 x 128), plus ||rk||^2 per (b,r)
// ---------------------------------------------------------------------------
__global__ __launch_bounds__(128) void rk_kernel(
    const float* __restrict__ xi, const float* __restrict__ Wrk,
    const float* __restrict__ brk, float* __restrict__ rk,
    float* __restrict__ rknorm) {
  const int b = blockIdx.x;
  const int tid = threadIdx.x;  // 128 threads = one rw each
  __shared__ float xs[Dd];
  __shared__ float rks[Rr * Ww];
  #pragma unroll
  for (int i = 0; i < Dd; i += 128) xs[i + tid] = xi[b * Dd + i + tid];
  __syncthreads();
  float acc = brk[tid];
  const float4* wr = reinterpret_cast<const float4*>(Wrk + (size_t)tid * Dd);
  #pragma unroll 4
  for (int i = 0; i < Dd / 4; ++i) {
    float4 wv = wr[i];
    acc = fmaf(wv.x, xs[4 * i + 0], acc);
    acc = fmaf(wv.y, xs[4 * i + 1], acc);
    acc = fmaf(wv.z, xs[4 * i + 2], acc);
    acc = fmaf(wv.w, xs[4 * i + 3], acc);
  }
  rk[b * Rr * Ww + tid] = acc;
  rks[tid] = acc;
  __syncthreads();
  if (tid < Rr) {
    float s = 0.f;
    #pragma unroll
    for (int j = 0; j < Ww; ++j) s = fmaf(rks[tid * Ww + j], rks[tid * Ww + j], s);
    rknorm[b * Rr + tid] = s;
  }
}

// ---------------------------------------------------------------------------
// Kernel 2: stream sparse[b] via LDS staging (coalesced), d2 for 4 heads,
//           per-block top-8 per head.
// ---------------------------------------------------------------------------
__global__ __launch_bounds__(TPB_A, 4) void topk_partial(
    const float* __restrict__ sparse, const float* __restrict__ rk,
    const float* __restrict__ rknorm, float* __restrict__ cand_d,
    int* __restrict__ cand_i) {
  const int b = blockIdx.y;
  const int tid = threadIdx.x;
  __shared__ float rk_s[Rr][Ww];
  __shared__ float rkn_s[Rr];
  // 256 rows x 8 float4-chunks, XOR-swizzled on chunk index: 32 KB
  __shared__ float4 tile[TPB_A * (Ww / 4)];
  if (tid < Rr * Ww) rk_s[tid >> 5][tid & 31] = rk[b * Rr * Ww + tid];
  if (tid < Rr) rkn_s[tid] = rknorm[b * Rr + tid];
  __syncthreads();

  const int m0 = blockIdx.x * ROWS_PER_BLOCK;
  const float* sb = sparse + (size_t)b * Mm * Ww;

  float d8[Rr][QQ];
  int i8[Rr][QQ];

  // 4 iterations; each stages 256 rows (32 KB) with fully coalesced loads:
  // lane i of a wave loads float4 #(i) of a contiguous 1 KB segment.
  for (int it = 0; it < QQ; ++it) {
    const float4* gsrc =
        reinterpret_cast<const float4*>(sb + (size_t)(m0 + it * TPB_A) * Ww);
    float4 stg[8];
    #pragma unroll
    for (int i = 0; i < 8; ++i) stg[i] = gsrc[i * TPB_A + tid];
    __syncthreads();  // previous iteration's tile reads complete
    #pragma unroll
    for (int i = 0; i < 8; ++i) {
      int p = i * TPB_A + tid;
      int row = p >> 3;
      int ch = p & 7;
      tile[row * 8 + (ch ^ (row & 7))] = stg[i];
    }
    __syncthreads();

    // thread owns tile-row == tid; swizzled reads spread over all banks
    float dot[Rr] = {0.f, 0.f, 0.f, 0.f};
    float ss = 0.f;
    #pragma unroll
    for (int j = 0; j < 8; ++j) {
      float4 v = tile[tid * 8 + (j ^ (tid & 7))];
      #pragma unroll
      for (int r = 0; r < Rr; ++r) {
        float4 rkv = *reinterpret_cast<const float4*>(&rk_s[r][4 * j]);
        dot[r] = fmaf(rkv.x, v.x, dot[r]);
        dot[r] = fmaf(rkv.y, v.y, dot[r]);
        dot[r] = fmaf(rkv.z, v.z, dot[r]);
        dot[r] = fmaf(rkv.w, v.w, dot[r]);
      }
      ss = fmaf(v.x, v.x, ss);
      ss = fmaf(v.y, v.y, ss);
      ss = fmaf(v.z, v.z, ss);
      ss = fmaf(v.w, v.w, ss);
    }
    #pragma unroll
    for (int r = 0; r < Rr; ++r) {
      d8[r][it] = rkn_s[r] - 2.f * dot[r] + ss;
      i8[r][it] = m0 + it * TPB_A + tid;
    }
  }

  // sort each per-thread 4-list ascending (static bubble network)
  #pragma unroll
  for (int r = 0; r < Rr; ++r)
    #pragma unroll
    for (int i = 0; i < QQ - 1; ++i)
      #pragma unroll
      for (int j = 0; j < QQ - 1 - i; ++j)
        if (d8[r][j + 1] < d8[r][j] ||
            (d8[r][j + 1] == d8[r][j] && i8[r][j + 1] < i8[r][j])) {
          float td = d8[r][j]; d8[r][j] = d8[r][j + 1]; d8[r][j + 1] = td;
          int ti = i8[r][j]; i8[r][j] = i8[r][j + 1]; i8[r][j + 1] = ti;
        }

  // --- block-level top-8 per r via 8 rounds of argmin extraction ---
  __shared__ float sv[TPB_A / 64];
  __shared__ int si[TPB_A / 64];
  const int lane = tid & 63;
  const int wid = tid >> 6;
  const float INF = __builtin_inff();
  #pragma unroll
  for (int r = 0; r < Rr; ++r) {
    #pragma unroll
    for (int k = 0; k < Kk; ++k) {
      float v = d8[r][0];
      int id = i8[r][0];
      #pragma unroll
      for (int off = 32; off; off >>= 1) {
        float ov = __shfl_xor(v, off);
        int oi = __shfl_xor(id, off);
        if (ov < v || (ov == v && oi < id)) { v = ov; id = oi; }
      }
      if (lane == 0) { sv[wid] = v; si[wid] = id; }
      __syncthreads();
      float bv = sv[0]; int bi = si[0];
      #pragma unroll
      for (int u = 1; u < TPB_A / 64; ++u)
        if (sv[u] < bv || (sv[u] == bv && si[u] < bi)) { bv = sv[u]; bi = si[u]; }
      if (tid == 0) {
        size_t o = ((size_t)(b * Rr + r) * NB_A + blockIdx.x) * Kk + k;
        cand_d[o] = bv;
        cand_i[o] = bi;
      }
      __syncthreads();  // protect sv/si before next round's write
      if (i8[r][0] == bi) {  // unique owner pops its head
        #pragma unroll
        for (int j = 0; j < QQ - 1; ++j) { d8[r][j] = d8[r][j + 1]; i8[r][j] = i8[r][j + 1]; }
        d8[r][QQ - 1] = INF;
        i8[r][QQ - 1] = -1;
      }
    }
  }
}

// ---------------------------------------------------------------------------
// Kernel 3: merge 64*8 candidates per (b,r) -> global top-8, weights, gather
// ---------------------------------------------------------------------------
__global__ __launch_bounds__(64) void topk_final(
    const float* __restrict__ sparse, const float* __restrict__ cand_d,
    const int* __restrict__ cand_i, float* __restrict__ out) {
  const int br = blockIdx.x;  // b*4 + r
  const int b = br >> 2;
  const int r = br & 3;
  const int lane = threadIdx.x;  // 64
  const float INF = __builtin_inff();

  float ld[Kk];
  int li[Kk];
  const float* cd = cand_d + (size_t)br * (NB_A * Kk);
  const int* ci = cand_i + (size_t)br * (NB_A * Kk);
  #pragma unroll
  for (int t = 0; t < Kk; ++t) {
    ld[t] = cd[t * 64 + lane];
    li[t] = ci[t * 64 + lane];
  }
  // sort per-lane 8-list ascending (static bubble network)
  #pragma unroll
  for (int i = 0; i < Kk - 1; ++i)
    #pragma unroll
    for (int j = 0; j < Kk - 1 - i; ++j)
      if (ld[j + 1] < ld[j] || (ld[j + 1] == ld[j] && li[j + 1] < li[j])) {
        float td = ld[j]; ld[j] = ld[j + 1]; ld[j + 1] = td;
        int ti = li[j]; li[j] = li[j + 1]; li[j + 1] = ti;
      }

  __shared__ float s_td[Kk];
  __shared__ int s_ti[Kk];
  #pragma unroll
  for (int k = 0; k < Kk; ++k) {
    float v = ld[0];
    int id = li[0];
    #pragma unroll
    for (int off = 32; off; off >>= 1) {  // butterfly: all lanes get the min
      float ov = __shfl_xor(v, off);
      int oi = __shfl_xor(id, off);
      if (ov < v || (ov == v && oi < id)) { v = ov; id = oi; }
    }
    if (lane == 0) { s_td[k] = v; s_ti[k] = id; }
    if (li[0] == id) {  // owner pops head
      #pragma unroll
      for (int j = 0; j < Kk - 1; ++j) { ld[j] = ld[j + 1]; li[j] = li[j + 1]; }
      ld[Kk - 1] = INF;
      li[Kk - 1] = -1;
    }
  }
  __syncthreads();

  // read_weights[r][b][k] = dist_k / dist_7  (dist ascending -> max is last)
  const float dmax = s_td[Kk - 1];
  if (lane < Kk)
    out[(size_t)Rr * Bb * Kk * Ww + ((size_t)r * Bb + b) * Kk + lane] =
        s_td[lane] / dmax;

  // read_vectors[r][b][k][j] = sparse[b][idx_k][j]
  const float* sbase = sparse + (size_t)b * Mm * Ww;
  #pragma unroll
  for (int t = 0; t < (Kk * Ww) / 64; ++t) {
    int e = t * 64 + lane;
    int k = e >> 5;
    int j = e & 31;
    out[(((size_t)r * Bb + b) * Kk + k) * Ww + j] =
        sbase[(size_t)s_ti[k] * Ww + j];
  }
}

// ---------------------------------------------------------------------------
extern "C" void kernel_launch(void* const* d_in, const int* in_sizes, int n_in,
                              void* d_out, int out_size, void* d_ws,
                              size_t ws_size, hipStream_t stream) {
  const float* xi = (const float*)d_in[0];
  const float* sparse = (const float*)d_in[1];
  const float* Wrk = (const float*)d_in[2];
  const float* brk = (const float*)d_in[3];
  float* out = (float*)d_out;

  char* ws = (char*)d_ws;
  float* rk = (float*)ws;                          // 32*128*4      = 16384 B
  float* rknorm = (float*)(ws + 16384);            // 128*4         = 512 B
  float* cand_d = (float*)(ws + 16896);            // 32*4*64*8*4   = 262144 B
  int* cand_i = (int*)(ws + 16896 + 262144);       // 262144 B

  rk_kernel<<<Bb, 128, 0, stream>>>(xi, Wrk, brk, rk, rknorm);
  dim3 gridA(NB_A, Bb);
  topk_partial<<<gridA, TPB_A, 0, stream>>>(sparse, rk, rknorm, cand_d, cand_i);
  topk_final<<<Bb * Rr, 64, 0, stream>>>(sparse, cand_d, cand_i, out);
}

// Round 3
// 387.392 us; speedup vs baseline: 1.6827x; 1.6827x over previous
//
#include <hip/hip_runtime.h>

// Problem constants (from reference setup_inputs)
constexpr int Bb = 32;      // batch
constexpr int Mm = 65536;   // memory slots
constexpr int Ww = 32;      // word width
constexpr int Rr = 4;       // read heads
constexpr int Dd = 256;     // d_in
constexpr int Kk = 8;       // K_NEIGHBORS

constexpr int NB_A = 64;                    // blocks per batch, phase A
constexpr int TPB_A = 256;                  // threads per block
constexpr int ROWS_PER_BLOCK = Mm / NB_A;   // 1024
constexpr int ROWS_PER_WAVE = ROWS_PER_BLOCK / 4;  // 256
constexpr int TT = 4;                       // candidate slots per thread
constexpr int UU = 8;                       // rotations per slot (TT*UU*8 = 256 rows)

// ---------------------------------------------------------------------------
// Kernel 1: read_keys = xi @ W_rk^T + b_rk  (32 x 128), plus ||rk||^2 per (b,r)
// ---------------------------------------------------------------------------
__global__ __launch_bounds__(128) void rk_kernel(
    const float* __restrict__ xi, const float* __restrict__ Wrk,
    const float* __restrict__ brk, float* __restrict__ rk,
    float* __restrict__ rknorm) {
  const int b = blockIdx.x;
  const int tid = threadIdx.x;  // 128 threads = one rw each
  __shared__ float xs[Dd];
  __shared__ float rks[Rr * Ww];
  #pragma unroll
  for (int i = 0; i < Dd; i += 128) xs[i + tid] = xi[b * Dd + i + tid];
  __syncthreads();
  float acc = brk[tid];
  const float4* wr = reinterpret_cast<const float4*>(Wrk + (size_t)tid * Dd);
  #pragma unroll 4
  for (int i = 0; i < Dd / 4; ++i) {
    float4 wv = wr[i];
    acc = fmaf(wv.x, xs[4 * i + 0], acc);
    acc = fmaf(wv.y, xs[4 * i + 1], acc);
    acc = fmaf(wv.z, xs[4 * i + 2], acc);
    acc = fmaf(wv.w, xs[4 * i + 3], acc);
  }
  rk[b * Rr * Ww + tid] = acc;
  rks[tid] = acc;
  __syncthreads();
  if (tid < Rr) {
    float s = 0.f;
    #pragma unroll
    for (int j = 0; j < Ww; ++j) s = fmaf(rks[tid * Ww + j], rks[tid * Ww + j], s);
    rknorm[b * Rr + tid] = s;
  }
}

// ---------------------------------------------------------------------------
// Kernel 2: wave-cooperative streaming. Each wave instruction loads a
// CONTIGUOUS 1 KB (8 rows x 128 B): lane = chunk (lane&7) of row (lane>>3).
// Every byte is consumed immediately -> no cache reuse needed, min fetch.
// Dots finished via 3-step shfl_xor within 8-lane groups. Row candidates
// rotate onto lane c==u so each thread keeps TT=4 static-slot candidates.
// Wave-local top-8 extraction (no barriers), then one LDS merge per r.
// ---------------------------------------------------------------------------
__global__ __launch_bounds__(TPB_A, 4) void topk_partial(
    const float* __restrict__ sparse, const float* __restrict__ rk,
    const float* __restrict__ rknorm, float* __restrict__ cand_d,
    int* __restrict__ cand_i) {
  const int b = blockIdx.y;
  const int tid = threadIdx.x;
  const int lane = tid & 63;
  const int wid = tid >> 6;
  const int c = lane & 7;   // chunk within row
  const int g = lane >> 3;  // row within 8-row group
  const float INF = __builtin_inff();

  __shared__ float rk_s[Rr][Ww];
  __shared__ float rkn_s[Rr];
  __shared__ float swv[4][Rr][Kk];
  __shared__ int swi[4][Rr][Kk];
  if (tid < Rr * Ww) rk_s[tid >> 5][tid & 31] = rk[b * Rr * Ww + tid];
  if (tid < Rr) rkn_s[tid] = rknorm[b * Rr + tid];
  __syncthreads();

  // hoist this lane's rk fragment (chunk c of each head) into registers
  float4 rkv[Rr];
  float rkn[Rr];
  #pragma unroll
  for (int r = 0; r < Rr; ++r) {
    rkv[r] = *reinterpret_cast<const float4*>(&rk_s[r][4 * c]);
    rkn[r] = rkn_s[r];
  }

  const int rowWave = blockIdx.x * ROWS_PER_BLOCK + wid * ROWS_PER_WAVE;
  const float4* sb4 =
      reinterpret_cast<const float4*>(sparse) + (size_t)b * Mm * (Ww / 4);

  float d8[Rr][TT];
  int i8[Rr][TT];
  #pragma unroll
  for (int r = 0; r < Rr; ++r)
    #pragma unroll
    for (int t = 0; t < TT; ++t) { d8[r][t] = INF; i8[r][t] = 0x7fffffff; }

  #pragma unroll
  for (int t = 0; t < TT; ++t) {
    #pragma unroll
    for (int u = 0; u < UU; ++u) {
      const int row0 = rowWave + (t * UU + u) * 8;  // 8 rows this iteration
      float4 v = sb4[(size_t)row0 * (Ww / 4) + lane];  // contiguous 1 KB/wave
      float pd[Rr], pss;
      #pragma unroll
      for (int r = 0; r < Rr; ++r) {
        pd[r] = rkv[r].x * v.x;
        pd[r] = fmaf(rkv[r].y, v.y, pd[r]);
        pd[r] = fmaf(rkv[r].z, v.z, pd[r]);
        pd[r] = fmaf(rkv[r].w, v.w, pd[r]);
      }
      pss = v.x * v.x;
      pss = fmaf(v.y, v.y, pss);
      pss = fmaf(v.z, v.z, pss);
      pss = fmaf(v.w, v.w, pss);
      // finish dot within each 8-lane group
      #pragma unroll
      for (int off = 1; off <= 4; off <<= 1) {
        #pragma unroll
        for (int r = 0; r < Rr; ++r) pd[r] += __shfl_xor(pd[r], off);
        pss += __shfl_xor(pss, off);
      }
      const bool keep = (c == u);
      const int rowIdx = row0 + g;
      #pragma unroll
      for (int r = 0; r < Rr; ++r) {
        float d2 = fmaf(-2.f, pd[r], rkn[r] + pss);
        d8[r][t] = keep ? d2 : d8[r][t];
        i8[r][t] = keep ? rowIdx : i8[r][t];
      }
    }
  }

  // sort each per-thread 4-list ascending (static bubble network)
  #pragma unroll
  for (int r = 0; r < Rr; ++r)
    #pragma unroll
    for (int i = 0; i < TT - 1; ++i)
      #pragma unroll
      for (int j = 0; j < TT - 1 - i; ++j)
        if (d8[r][j + 1] < d8[r][j] ||
            (d8[r][j + 1] == d8[r][j] && i8[r][j + 1] < i8[r][j])) {
          float td = d8[r][j]; d8[r][j] = d8[r][j + 1]; d8[r][j + 1] = td;
          int ti = i8[r][j]; i8[r][j] = i8[r][j + 1]; i8[r][j + 1] = ti;
        }

  // --- wave-local top-8 per r (no block barriers) ---
  #pragma unroll
  for (int r = 0; r < Rr; ++r) {
    #pragma unroll
    for (int k = 0; k < Kk; ++k) {
      float v = d8[r][0];
      int id = i8[r][0];
      #pragma unroll
      for (int off = 32; off; off >>= 1) {
        float ov = __shfl_xor(v, off);
        int oi = __shfl_xor(id, off);
        if (ov < v || (ov == v && oi < id)) { v = ov; id = oi; }
      }
      if (lane == 0) { swv[wid][r][k] = v; swi[wid][r][k] = id; }
      if (i8[r][0] == id) {  // unique owner pops its head
        #pragma unroll
        for (int j = 0; j < TT - 1; ++j) { d8[r][j] = d8[r][j + 1]; i8[r][j] = i8[r][j + 1]; }
        d8[r][TT - 1] = INF;
        i8[r][TT - 1] = 0x7fffffff;
      }
    }
  }
  __syncthreads();

  // --- merge 4 waves x 8 -> block top-8; wave `wid` handles r = wid ---
  {
    const int r = wid;
    float v = INF;
    int id = 0x7fffffff;
    if (lane < 32) { v = swv[lane >> 3][r][lane & 7]; id = swi[lane >> 3][r][lane & 7]; }
    size_t o = ((size_t)(b * Rr + r) * NB_A + blockIdx.x) * Kk;
    #pragma unroll
    for (int k = 0; k < Kk; ++k) {
      float bv = v;
      int bi = id;
      #pragma unroll
      for (int off = 32; off; off >>= 1) {
        float ov = __shfl_xor(bv, off);
        int oi = __shfl_xor(bi, off);
        if (ov < bv || (ov == bv && oi < bi)) { bv = ov; bi = oi; }
      }
      if (lane == 0) { cand_d[o + k] = bv; cand_i[o + k] = bi; }
      if (v == bv && id == bi) { v = INF; id = 0x7fffffff; }  // pop self
    }
  }
}

// ---------------------------------------------------------------------------
// Kernel 3: merge 64*8 candidates per (b,r) -> global top-8, weights, gather
// ---------------------------------------------------------------------------
__global__ __launch_bounds__(64) void topk_final(
    const float* __restrict__ sparse, const float* __restrict__ cand_d,
    const int* __restrict__ cand_i, float* __restrict__ out) {
  const int br = blockIdx.x;  // b*4 + r
  const int b = br >> 2;
  const int r = br & 3;
  const int lane = threadIdx.x;  // 64
  const float INF = __builtin_inff();

  float ld[Kk];
  int li[Kk];
  const float* cd = cand_d + (size_t)br * (NB_A * Kk);
  const int* ci = cand_i + (size_t)br * (NB_A * Kk);
  #pragma unroll
  for (int t = 0; t < Kk; ++t) {
    ld[t] = cd[t * 64 + lane];
    li[t] = ci[t * 64 + lane];
  }
  // sort per-lane 8-list ascending (static bubble network)
  #pragma unroll
  for (int i = 0; i < Kk - 1; ++i)
    #pragma unroll
    for (int j = 0; j < Kk - 1 - i; ++j)
      if (ld[j + 1] < ld[j] || (ld[j + 1] == ld[j] && li[j + 1] < li[j])) {
        float td = ld[j]; ld[j] = ld[j + 1]; ld[j + 1] = td;
        int ti = li[j]; li[j] = li[j + 1]; li[j + 1] = ti;
      }

  __shared__ float s_td[Kk];
  __shared__ int s_ti[Kk];
  #pragma unroll
  for (int k = 0; k < Kk; ++k) {
    float v = ld[0];
    int id = li[0];
    #pragma unroll
    for (int off = 32; off; off >>= 1) {  // butterfly: all lanes get the min
      float ov = __shfl_xor(v, off);
      int oi = __shfl_xor(id, off);
      if (ov < v || (ov == v && oi < id)) { v = ov; id = oi; }
    }
    if (lane == 0) { s_td[k] = v; s_ti[k] = id; }
    if (li[0] == id) {  // owner pops head
      #pragma unroll
      for (int j = 0; j < Kk - 1; ++j) { ld[j] = ld[j + 1]; li[j] = li[j + 1]; }
      ld[Kk - 1] = INF;
      li[Kk - 1] = -1;
    }
  }
  __syncthreads();

  // read_weights[r][b][k] = dist_k / dist_7  (dist ascending -> max is last)
  const float dmax = s_td[Kk - 1];
  if (lane < Kk)
    out[(size_t)Rr * Bb * Kk * Ww + ((size_t)r * Bb + b) * Kk + lane] =
        s_td[lane] / dmax;

  // read_vectors[r][b][k][j] = sparse[b][idx_k][j]
  const float* sbase = sparse + (size_t)b * Mm * Ww;
  #pragma unroll
  for (int t = 0; t < (Kk * Ww) / 64; ++t) {
    int e = t * 64 + lane;
    int k = e >> 5;
    int j = e & 31;
    out[(((size_t)r * Bb + b) * Kk + k) * Ww + j] =
        sbase[(size_t)s_ti[k] * Ww + j];
  }
}

// ---------------------------------------------------------------------------
extern "C" void kernel_launch(void* const* d_in, const int* in_sizes, int n_in,
                              void* d_out, int out_size, void* d_ws,
                              size_t ws_size, hipStream_t stream) {
  const float* xi = (const float*)d_in[0];
  const float* sparse = (const float*)d_in[1];
  const float* Wrk = (const float*)d_in[2];
  const float* brk = (const float*)d_in[3];
  float* out = (float*)d_out;

  char* ws = (char*)d_ws;
  float* rk = (float*)ws;                          // 32*128*4      = 16384 B
  float* rknorm = (float*)(ws + 16384);            // 128*4         = 512 B
  float* cand_d = (float*)(ws + 16896);            // 32*4*64*8*4   = 262144 B
  int* cand_i = (int*)(ws + 16896 + 262144);       // 262144 B

  rk_kernel<<<Bb, 128, 0, stream>>>(xi, Wrk, brk, rk, rknorm);
  dim3 gridA(NB_A, Bb);
  topk_partial<<<gridA, TPB_A, 0, stream>>>(sparse, rk, rknorm, cand_d, cand_i);
  topk_final<<<Bb * Rr, 64, 0, stream>>>(sparse, cand_d, cand_i, out);
}

// Round 4
// 174.106 us; speedup vs baseline: 3.7441x; 2.2250x over previous
//
#include <hip/hip_runtime.h>

// Problem constants (from reference setup_inputs)
constexpr int Bb = 32;      // batch
constexpr int Mm = 65536;   // memory slots
constexpr int Ww = 32;      // word width
constexpr int Rr = 4;       // read heads
constexpr int Dd = 256;     // d_in
constexpr int Kk = 8;       // K_NEIGHBORS

constexpr int NB_A = 64;                    // blocks per batch, phase A
constexpr int TPB_A = 256;                  // threads per block
constexpr int ROWS_PER_BLOCK = Mm / NB_A;   // 1024
constexpr int ROWS_PER_WAVE = ROWS_PER_BLOCK / 4;  // 256
constexpr int TT = 4;                       // candidate slots per thread
constexpr int UU = 8;                       // rotations per slot (TT*UU*8 = 256 rows)

// ---------------------------------------------------------------------------
// Kernel 1: read_keys = xi @ W_rk^T + b_rk  (32 x 128), plus ||rk||^2 per (b,r)
// ---------------------------------------------------------------------------
__global__ __launch_bounds__(128) void rk_kernel(
    const float* __restrict__ xi, const float* __restrict__ Wrk,
    const float* __restrict__ brk, float* __restrict__ rk,
    float* __restrict__ rknorm) {
  const int b = blockIdx.x;
  const int tid = threadIdx.x;  // 128 threads = one rw each
  __shared__ float xs[Dd];
  __shared__ float rks[Rr * Ww];
  #pragma unroll
  for (int i = 0; i < Dd; i += 128) xs[i + tid] = xi[b * Dd + i + tid];
  __syncthreads();
  float acc = brk[tid];
  const float4* wr = reinterpret_cast<const float4*>(Wrk + (size_t)tid * Dd);
  #pragma unroll 4
  for (int i = 0; i < Dd / 4; ++i) {
    float4 wv = wr[i];
    acc = fmaf(wv.x, xs[4 * i + 0], acc);
    acc = fmaf(wv.y, xs[4 * i + 1], acc);
    acc = fmaf(wv.z, xs[4 * i + 2], acc);
    acc = fmaf(wv.w, xs[4 * i + 3], acc);
  }
  rk[b * Rr * Ww + tid] = acc;
  rks[tid] = acc;
  __syncthreads();
  if (tid < Rr) {
    float s = 0.f;
    #pragma unroll
    for (int j = 0; j < Ww; ++j) s = fmaf(rks[tid * Ww + j], rks[tid * Ww + j], s);
    rknorm[b * Rr + tid] = s;
  }
}

// ---------------------------------------------------------------------------
// Kernel 2: wave-cooperative streaming. Each wave instruction loads a
// CONTIGUOUS 1 KB (8 rows x 128 B): lane = chunk (lane&7) of row (lane>>3).
// Every byte is consumed immediately -> no cache reuse needed, min fetch.
// Dots finished via 3-step shfl_xor within 8-lane groups; lane keeps row
// (t*8+c)*8+g in slot t (when u==c) -> slot index is STATIC, row index is
// base + t*64 (recomputed, no i8 array). Top-8 via 8 argmin rounds with
// static per-slot clear (no dynamic indexing -> no scratch spill).
// ---------------------------------------------------------------------------
__global__ __launch_bounds__(TPB_A, 2) void topk_partial(
    const float* __restrict__ sparse, const float* __restrict__ rk,
    const float* __restrict__ rknorm, float* __restrict__ cand_d,
    int* __restrict__ cand_i) {
  const int b = blockIdx.y;
  const int tid = threadIdx.x;
  const int lane = tid & 63;
  const int wid = tid >> 6;
  const int c = lane & 7;   // chunk within row
  const int g = lane >> 3;  // row within 8-row group
  const float INF = __builtin_inff();

  __shared__ float rk_s[Rr][Ww];
  __shared__ float rkn_s[Rr];
  __shared__ float swv[4][Rr][Kk];
  __shared__ int swi[4][Rr][Kk];
  if (tid < Rr * Ww) rk_s[tid >> 5][tid & 31] = rk[b * Rr * Ww + tid];
  if (tid < Rr) rkn_s[tid] = rknorm[b * Rr + tid];
  __syncthreads();

  // hoist this lane's rk fragment (chunk c of each head) into registers
  float4 rkv[Rr];
  float rkn[Rr];
  #pragma unroll
  for (int r = 0; r < Rr; ++r) {
    rkv[r] = *reinterpret_cast<const float4*>(&rk_s[r][4 * c]);
    rkn[r] = rkn_s[r];
  }

  const int rowWave = blockIdx.x * ROWS_PER_BLOCK + wid * ROWS_PER_WAVE;
  const int base = rowWave + c * 8 + g;  // row held in slot t is base + t*64
  const float4* sb4 =
      reinterpret_cast<const float4*>(sparse) + (size_t)b * Mm * (Ww / 4);

  float d8[Rr][TT];
  #pragma unroll
  for (int r = 0; r < Rr; ++r)
    #pragma unroll
    for (int t = 0; t < TT; ++t) d8[r][t] = INF;

  #pragma unroll
  for (int t = 0; t < TT; ++t) {
    #pragma unroll
    for (int u = 0; u < UU; ++u) {
      const int row0 = rowWave + (t * UU + u) * 8;  // 8 rows this iteration
      float4 v = sb4[(size_t)row0 * (Ww / 4) + lane];  // contiguous 1 KB/wave
      float pd[Rr], pss;
      #pragma unroll
      for (int r = 0; r < Rr; ++r) {
        pd[r] = rkv[r].x * v.x;
        pd[r] = fmaf(rkv[r].y, v.y, pd[r]);
        pd[r] = fmaf(rkv[r].z, v.z, pd[r]);
        pd[r] = fmaf(rkv[r].w, v.w, pd[r]);
      }
      pss = v.x * v.x;
      pss = fmaf(v.y, v.y, pss);
      pss = fmaf(v.z, v.z, pss);
      pss = fmaf(v.w, v.w, pss);
      // finish dot within each 8-lane group
      #pragma unroll
      for (int off = 1; off <= 4; off <<= 1) {
        #pragma unroll
        for (int r = 0; r < Rr; ++r) pd[r] += __shfl_xor(pd[r], off);
        pss += __shfl_xor(pss, off);
      }
      const bool keep = (c == u);
      #pragma unroll
      for (int r = 0; r < Rr; ++r) {
        float d2 = fmaf(-2.f, pd[r], rkn[r] + pss);
        d8[r][t] = keep ? d2 : d8[r][t];
      }
    }
  }

  // --- wave-local top-8 per r: 8 rounds of {static 4-slot argmin ->
  //     butterfly -> static per-slot clear}; no dynamic indexing ---
  #pragma unroll
  for (int r = 0; r < Rr; ++r) {
    #pragma unroll
    for (int k = 0; k < Kk; ++k) {
      // per-lane argmin over the 4 static slots (idx = base + t*64,
      // ascending in t, so scanning with strict < keeps lowest idx on ties)
      float lv = d8[r][0];
      int lidx = base;
      #pragma unroll
      for (int t = 1; t < TT; ++t)
        if (d8[r][t] < lv) { lv = d8[r][t]; lidx = base + t * 64; }
      // wave butterfly argmin with index tie-break
      float bv = lv;
      int bi = lidx;
      #pragma unroll
      for (int off = 32; off; off >>= 1) {
        float ov = __shfl_xor(bv, off);
        int oi = __shfl_xor(bi, off);
        if (ov < bv || (ov == bv && oi < bi)) { bv = ov; bi = oi; }
      }
      if (lane == 0) { swv[wid][r][k] = bv; swi[wid][r][k] = bi; }
      // winner's slot (value AND row both match) -> INF; static indexing
      #pragma unroll
      for (int t = 0; t < TT; ++t) {
        bool clr = (d8[r][t] == bv) && (base + t * 64 == bi);
        d8[r][t] = clr ? INF : d8[r][t];
      }
    }
  }
  __syncthreads();

  // --- merge 4 waves x 8 -> block top-8; wave `wid` handles r = wid ---
  {
    const int r = wid;
    float v = INF;
    int id = 0x7fffffff;
    if (lane < 32) { v = swv[lane >> 3][r][lane & 7]; id = swi[lane >> 3][r][lane & 7]; }
    size_t o = ((size_t)(b * Rr + r) * NB_A + blockIdx.x) * Kk;
    #pragma unroll
    for (int k = 0; k < Kk; ++k) {
      float bv = v;
      int bi = id;
      #pragma unroll
      for (int off = 32; off; off >>= 1) {
        float ov = __shfl_xor(bv, off);
        int oi = __shfl_xor(bi, off);
        if (ov < bv || (ov == bv && oi < bi)) { bv = ov; bi = oi; }
      }
      if (lane == 0) { cand_d[o + k] = bv; cand_i[o + k] = bi; }
      if (v == bv && id == bi) { v = INF; id = 0x7fffffff; }  // pop self
    }
  }
}

// ---------------------------------------------------------------------------
// Kernel 3: merge 64*8 candidates per (b,r) -> global top-8, weights, gather
// ---------------------------------------------------------------------------
__global__ __launch_bounds__(64) void topk_final(
    const float* __restrict__ sparse, const float* __restrict__ cand_d,
    const int* __restrict__ cand_i, float* __restrict__ out) {
  const int br = blockIdx.x;  // b*4 + r
  const int b = br >> 2;
  const int r = br & 3;
  const int lane = threadIdx.x;  // 64
  const float INF = __builtin_inff();

  float ld[Kk];
  int li[Kk];
  const float* cd = cand_d + (size_t)br * (NB_A * Kk);
  const int* ci = cand_i + (size_t)br * (NB_A * Kk);
  #pragma unroll
  for (int t = 0; t < Kk; ++t) {
    ld[t] = cd[t * 64 + lane];
    li[t] = ci[t * 64 + lane];
  }
  // sort per-lane 8-list ascending (static bubble network)
  #pragma unroll
  for (int i = 0; i < Kk - 1; ++i)
    #pragma unroll
    for (int j = 0; j < Kk - 1 - i; ++j)
      if (ld[j + 1] < ld[j] || (ld[j + 1] == ld[j] && li[j + 1] < li[j])) {
        float td = ld[j]; ld[j] = ld[j + 1]; ld[j + 1] = td;
        int ti = li[j]; li[j] = li[j + 1]; li[j + 1] = ti;
      }

  __shared__ float s_td[Kk];
  __shared__ int s_ti[Kk];
  #pragma unroll
  for (int k = 0; k < Kk; ++k) {
    float v = ld[0];
    int id = li[0];
    #pragma unroll
    for (int off = 32; off; off >>= 1) {  // butterfly: all lanes get the min
      float ov = __shfl_xor(v, off);
      int oi = __shfl_xor(id, off);
      if (ov < v || (ov == v && oi < id)) { v = ov; id = oi; }
    }
    if (lane == 0) { s_td[k] = v; s_ti[k] = id; }
    if (li[0] == id) {  // owner pops head
      #pragma unroll
      for (int j = 0; j < Kk - 1; ++j) { ld[j] = ld[j + 1]; li[j] = li[j + 1]; }
      ld[Kk - 1] = INF;
      li[Kk - 1] = -1;
    }
  }
  __syncthreads();

  // read_weights[r][b][k] = dist_k / dist_7  (dist ascending -> max is last)
  const float dmax = s_td[Kk - 1];
  if (lane < Kk)
    out[(size_t)Rr * Bb * Kk * Ww + ((size_t)r * Bb + b) * Kk + lane] =
        s_td[lane] / dmax;

  // read_vectors[r][b][k][j] = sparse[b][idx_k][j]
  const float* sbase = sparse + (size_t)b * Mm * Ww;
  #pragma unroll
  for (int t = 0; t < (Kk * Ww) / 64; ++t) {
    int e = t * 64 + lane;
    int k = e >> 5;
    int j = e & 31;
    out[(((size_t)r * Bb + b) * Kk + k) * Ww + j] =
        sbase[(size_t)s_ti[k] * Ww + j];
  }
}

// ---------------------------------------------------------------------------
extern "C" void kernel_launch(void* const* d_in, const int* in_sizes, int n_in,
                              void* d_out, int out_size, void* d_ws,
                              size_t ws_size, hipStream_t stream) {
  const float* xi = (const float*)d_in[0];
  const float* sparse = (const float*)d_in[1];
  const float* Wrk = (const float*)d_in[2];
  const float* brk = (const float*)d_in[3];
  float* out = (float*)d_out;

  char* ws = (char*)d_ws;
  float* rk = (float*)ws;                          // 32*128*4      = 16384 B
  float* rknorm = (float*)(ws + 16384);            // 128*4         = 512 B
  float* cand_d = (float*)(ws + 16896);            // 32*4*64*8*4   = 262144 B
  int* cand_i = (int*)(ws + 16896 + 262144);       // 262144 B

  rk_kernel<<<Bb, 128, 0, stream>>>(xi, Wrk, brk, rk, rknorm);
  dim3 gridA(NB_A, Bb);
  topk_partial<<<gridA, TPB_A, 0, stream>>>(sparse, rk, rknorm, cand_d, cand_i);
  topk_final<<<Bb * Rr, 64, 0, stream>>>(sparse, cand_d, cand_i, out);
}